// Round 5
// baseline (222.299 us; speedup 1.0000x reference)
//
#include <hip/hip_runtime.h>
#include <hip/hip_bf16.h>

#define NGRAPH 16
#define NNODE 1024
#define DDIM 64

typedef __attribute__((ext_vector_type(8))) short bf16x8;
typedef __attribute__((ext_vector_type(4))) float f32x4;

// ---- workspace layout (float offsets) ----
#define OFF_ROWSUM 0            // 16384
#define OFF_DIAG   16384        // 16384
#define OFF_P1     32768        // 16384
#define OFF_R      49152        // 16384
#define OFF_CS     65536        // 16*8*64 = 8192
#define OFF_S      73728        // 16 (+ pad)
#define OFF_S2P    75840        // 16384
#define OFF_R2P    92224        // 16384
#define OFF_BASE0  110656       // 16*1024*64 = 1048576
#define OFF_X2T    1159232      // ushort area: 16*64*1024 ushorts = 524288 floats

__device__ __forceinline__ unsigned short f2bf(float f) {
    unsigned int u = __float_as_uint(f);
    u = (u + 0x7fffu + ((u >> 16) & 1u)) >> 16;
    return (unsigned short)u;
}

__device__ __forceinline__ float wave_reduce(float v) {
    #pragma unroll
    for (int off = 32; off; off >>= 1) v += __shfl_down(v, off, 64);
    return v;
}

// ---------------- kA: A row sums + diag  |  X column sums + p1 = X @ wA1 ----------------
__global__ __launch_bounds__(256) void kA_stats(const float* __restrict__ A,
                                                const float* __restrict__ X,
                                                const float* __restrict__ wA1,
                                                float* __restrict__ rowsum,
                                                float* __restrict__ diagv,
                                                float* __restrict__ p1,
                                                float* __restrict__ colsum_part) {
    if (blockIdx.x < NGRAPH * NNODE / 4) {
        int row  = blockIdx.x * 4 + (threadIdx.x >> 6);
        int lane = threadIdx.x & 63;
        const float4* b4 = (const float4*)(A + (size_t)row * NNODE);
        float sum = 0.f;
        #pragma unroll
        for (int it = 0; it < 4; ++it) {
            float4 v = b4[lane + it * 64];
            sum += v.x + v.y + v.z + v.w;
        }
        sum = wave_reduce(sum);
        if (lane == 0) {
            rowsum[row] = sum;
            int i = row & (NNODE - 1);
            diagv[row] = ((const float*)b4)[i];
        }
    } else {
        int bid  = blockIdx.x - NGRAPH * NNODE / 4;
        int b    = bid >> 3;
        int blk  = bid & 7;
        int wv   = threadIdx.x >> 6;
        int lane = threadIdx.x & 63;
        float w = wA1[lane];
        float cs = 0.f;
        int row0 = blk * 128 + wv * 32;
        const float* Xb = X + (size_t)b * NNODE * DDIM;
        for (int rI = 0; rI < 32; ++rI) {
            int i = row0 + rI;
            float x = Xb[i * DDIM + lane];
            cs += x;
            float v = wave_reduce(x * w);
            if (lane == 0) p1[b * NNODE + i] = v;
        }
        __shared__ float csl[4][64];
        csl[wv][lane] = cs;
        __syncthreads();
        if (threadIdx.x < 64) {
            float t = csl[0][lane] + csl[1][lane] + csl[2][lane] + csl[3][lane];
            colsum_part[(b * 8 + blk) * 64 + lane] = t;
        }
    }
}

// ---------------- kB: per-graph stats (recomputed per block) + per-node transforms ----------------
__global__ __launch_bounds__(256) void kB_nodes(const float* __restrict__ X,
                                                const float* __restrict__ coeffs,
                                                const float* __restrict__ wA2,
                                                const float* __restrict__ w11,
                                                const float* __restrict__ w12,
                                                const float* __restrict__ w13,
                                                const float* __restrict__ w14,
                                                const float* __restrict__ w15,
                                                const float* __restrict__ w16,
                                                const float* __restrict__ w21,
                                                const float* __restrict__ w22,
                                                const float* __restrict__ w23,
                                                const float* __restrict__ w24,
                                                const float* __restrict__ w25,
                                                const float* __restrict__ w26,
                                                const float* __restrict__ rowsum,
                                                const float* __restrict__ diagv,
                                                const float* __restrict__ colsum_part,
                                                const float* __restrict__ p1g,
                                                float* __restrict__ rws,
                                                float* __restrict__ base0,
                                                unsigned short* __restrict__ x2tg,
                                                float* __restrict__ S2part,
                                                float* __restrict__ R2part,
                                                float* __restrict__ sArr) {
    __shared__ float Xl[64][68];
    __shared__ float w1l[64][68];
    __shared__ float w2l[64][68];
    __shared__ unsigned short X2Tl[64][68];
    __shared__ float rm_l[64], dg_l[64], r_l[64];
    __shared__ float redS[4][64], redR[4][64];
    __shared__ float redA[4], redD[4];
    __shared__ float mxs[64], p2s;
    __shared__ float pg1_l[64], pg2_l[64];

    int b    = blockIdx.x >> 4;
    int tile = blockIdx.x & 15;
    int i0   = tile * 64;
    int tid  = threadIdx.x;
    int e    = tid & 63;
    int wv   = tid >> 6;

    // --- stage X tile + weights ---
    const float* Xg = X + (size_t)b * (NNODE * DDIM) + (size_t)i0 * DDIM;
    #pragma unroll
    for (int it = 0; it < 4; ++it) {
        int g   = it * 256 + tid;
        int row = g >> 4;
        int c4  = (g & 15) << 2;
        float4 v  = ((const float4*)Xg)[g];
        *(float4*)&Xl[row][c4] = v;
        float4 v1 = ((const float4*)w11)[g];
        *(float4*)&w1l[row][c4] = v1;
        float4 v2 = ((const float4*)w21)[g];
        *(float4*)&w2l[row][c4] = v2;
    }

    // --- per-graph scalar stats (every block recomputes; cheap) ---
    float sa = 0.f, sd = 0.f;
    for (int i = tid; i < NNODE; i += 256) {
        sa += rowsum[b * NNODE + i];
        sd += diagv[b * NNODE + i];
    }
    sa = wave_reduce(sa); sd = wave_reduce(sd);
    if (e == 0) { redA[wv] = sa; redD[wv] = sd; }
    if (tid < 64) {
        float mx = 0.f;
        for (int k = 0; k < 8; ++k) mx += colsum_part[(b * 8 + k) * 64 + tid];
        mxs[tid] = mx * (1.f / (float)NNODE);
    }
    __syncthreads();
    float mean_all  = (redA[0] + redA[1] + redA[2] + redA[3]) * (1.f / ((float)NNODE * (float)NNODE));
    float mean_diag = (redD[0] + redD[1] + redD[2] + redD[3]) * (1.f / (float)NNODE);
    if (tid < 64) {
        float v = wave_reduce(mxs[tid] * wA2[tid]);
        if (tid == 0) p2s = v;
    }
    if (tid < 64) {
        float a1 = 0.f, a2 = 0.f;
        for (int d = 0; d < 64; ++d) {
            float m = mxs[d];
            a1 += m * w12[tid * 64 + d];
            a2 += m * w22[tid * 64 + d];
        }
        pg1_l[tid] = a1 + mean_diag * w15[tid] + mean_all * w16[tid];
        pg2_l[tid] = a2 + mean_diag * w25[tid] + mean_all * w26[tid];
    }
    float c3 = coeffs[3], c4c = coeffs[4];
    if (tid < 64) {
        float rs  = rowsum[b * NNODE + i0 + tid];
        float dgv = diagv[b * NNODE + i0 + tid];
        float rmv = rs * (1.f / (float)NNODE);
        rm_l[tid] = rmv;
        dg_l[tid] = dgv;
        float rv = c3 * rmv + c4c * dgv + p1g[b * NNODE + i0 + tid];
        r_l[tid] = rv;
        rws[b * NNODE + i0 + tid] = rv;
    }
    __syncthreads();
    if (tile == 0 && tid == 0)
        sArr[b] = coeffs[1] * mean_all + coeffs[2] * mean_diag + p2s;

    float w13e = w13[e], w14e = w14[e], w23e = w23[e], w24e = w24[e];
    float pg1e = pg1_l[e], pg2e = pg2_l[e];

    float acc1[16], acc2[16];
    #pragma unroll
    for (int t = 0; t < 16; ++t) { acc1[t] = 0.f; acc2[t] = 0.f; }

    for (int d0 = 0; d0 < 64; d0 += 4) {
        float4 w1v = *(const float4*)&w1l[e][d0];
        float4 w2v = *(const float4*)&w2l[e][d0];
        #pragma unroll
        for (int t = 0; t < 16; ++t) {
            int li = wv + 4 * t;
            float4 xv = *(const float4*)&Xl[li][d0];
            acc1[t] += xv.x * w1v.x + xv.y * w1v.y + xv.z * w1v.z + xv.w * w1v.w;
            acc2[t] += xv.x * w2v.x + xv.y * w2v.y + xv.z * w2v.z + xv.w * w2v.w;
        }
    }

    float s2acc = 0.f, r2acc = 0.f;
    #pragma unroll
    for (int t = 0; t < 16; ++t) {
        int li = wv + 4 * t;
        int i  = i0 + li;
        float rmv = rm_l[li], dgv = dg_l[li];
        float x2t = acc2[t] + rmv * w23e + dgv * w24e + pg2e;
        float b0  = acc1[t] + rmv * w13e + dgv * w14e + pg1e;
        base0[((size_t)(b * NNODE + i)) * 64 + e] = b0;
        X2Tl[e][li] = f2bf(x2t);
        s2acc += x2t;
        r2acc += r_l[li] * x2t;
    }
    redS[wv][e] = s2acc;
    redR[wv][e] = r2acc;
    __syncthreads();

    for (int k = 0; k < 16; ++k) {
        int ep = wv * 16 + k;
        unsigned short v = X2Tl[ep][e];
        x2tg[((size_t)(b * 64 + ep)) * NNODE + i0 + e] = v;
    }
    if (tid < 64) {
        float s2 = redS[0][tid] + redS[1][tid] + redS[2][tid] + redS[3][tid];
        float r2 = redR[0][tid] + redR[1][tid] + redR[2][tid] + redR[3][tid];
        S2part[(b * 16 + tile) * 64 + tid] = s2;
        R2part[(b * 16 + tile) * 64 + tid] = r2;
    }
}

// ---------------- kC: barrier-free fused A_t + bf16 MFMA c0*(A @ X2t) + epilogue ----------------
// 1024 blocks x 256 threads. Each wave is autonomous: loads its own A-fragments
// straight from global (L1/L2 absorb the 4x intra-block re-read), converts to
// bf16 in-register, MFMAs against B-fragments from L2-resident x2tg.
// Wave wv transforms+stores the A_t columns of frag ks==wv (disjoint cover).
// No __syncthreads in the K-loop -> no vmcnt(0) barrier drains.
__global__ __launch_bounds__(256, 4) void kC_main(const float* __restrict__ A,
                                               const float* __restrict__ coeffs,
                                               const float* __restrict__ sArr,
                                               const float* __restrict__ rArr,
                                               const unsigned short* __restrict__ x2tg,
                                               const float* __restrict__ base0,
                                               const float* __restrict__ S2part,
                                               const float* __restrict__ R2part,
                                               float* __restrict__ At,
                                               float* __restrict__ outp) {
    __shared__ float r_lds[1024];
    __shared__ float s2_lds[64], r2_lds[64];

    int b    = blockIdx.x >> 6;      // 64 tiles of 16 rows per graph
    int tile = blockIdx.x & 63;
    int i0   = tile * 16;
    int tid  = threadIdx.x;

    // stage r (1024 floats); threads<64 also reduce S2/R2 partials
    float4 rv = ((const float4*)(rArr + b * NNODE))[tid];
    *(float4*)&r_lds[tid * 4] = rv;
    if (tid < 64) {
        float s2 = 0.f, r2 = 0.f;
        #pragma unroll
        for (int t = 0; t < 16; ++t) {
            s2 += S2part[(b * 16 + t) * 64 + tid];
            r2 += R2part[(b * 16 + t) * 64 + tid];
        }
        s2_lds[tid] = s2 * (1.f / (float)NNODE);
        r2_lds[tid] = r2 * (1.f / (float)NNODE);
    }

    int lane = tid & 63, wv = tid >> 6;    // wv 0..3
    int m = lane & 15, quad = lane >> 4;
    int e = wv * 16 + m;
    int qo = quad * 8;

    const float* Arow            = A    + ((size_t)(b * NNODE + i0 + m)) * NNODE;
    float*       Atrow           = At   + ((size_t)(b * NNODE + i0 + m)) * NNODE;
    const unsigned short* Bg     = x2tg + ((size_t)(b * 64 + e)) * NNODE;

    float sb  = sArr[b];
    float c0  = coeffs[0];
    float c0n = c0 * (1.f / (float)NNODE);

    __syncthreads();   // r_lds / s2_lds ready — the only barrier

    float bse = sb + r_lds[i0 + m];

    f32x4 acc = {0.f, 0.f, 0.f, 0.f};

    for (int kt = 0; kt < 8; ++kt) {
        int k0 = kt * 128;
        #pragma unroll
        for (int j = 0; j < 4; ++j) {
            int ks = (wv + j) & 3;          // own frag first (wave-uniform)
            int c  = k0 + ks * 32 + qo;
            float4 a0 = *(const float4*)(Arow + c);
            float4 a1 = *(const float4*)(Arow + c + 4);
            bf16x8 bv = *(const bf16x8*)(Bg + c);

            if (j == 0) {
                // this wave owns A_t for these columns
                float4 rj0 = *(const float4*)&r_lds[c];
                float4 rj1 = *(const float4*)&r_lds[c + 4];
                f32x4 t0, t1;
                t0.x = fmaf(c0, a0.x, bse + rj0.x);
                t0.y = fmaf(c0, a0.y, bse + rj0.y);
                t0.z = fmaf(c0, a0.z, bse + rj0.z);
                t0.w = fmaf(c0, a0.w, bse + rj0.w);
                t1.x = fmaf(c0, a1.x, bse + rj1.x);
                t1.y = fmaf(c0, a1.y, bse + rj1.y);
                t1.z = fmaf(c0, a1.z, bse + rj1.z);
                t1.w = fmaf(c0, a1.w, bse + rj1.w);
                *(f32x4*)(Atrow + c)     = t0;
                *(f32x4*)(Atrow + c + 4) = t1;
            }

            union { uint4 u; bf16x8 v; } cvt;
            cvt.u.x = (unsigned int)f2bf(a0.x) | ((unsigned int)f2bf(a0.y) << 16);
            cvt.u.y = (unsigned int)f2bf(a0.z) | ((unsigned int)f2bf(a0.w) << 16);
            cvt.u.z = (unsigned int)f2bf(a1.x) | ((unsigned int)f2bf(a1.y) << 16);
            cvt.u.w = (unsigned int)f2bf(a1.z) | ((unsigned int)f2bf(a1.w) << 16);
            acc = __builtin_amdgcn_mfma_f32_16x16x32_bf16(cvt.v, bv, acc, 0, 0, 0);
        }
    }

    // ---- epilogue: out = c0/n * (A@X2t) + base0 + (s + r_i)*S2/n + R2/n ----
    float s2 = s2_lds[e];
    float r2 = r2_lds[e];
    #pragma unroll
    for (int reg = 0; reg < 4; ++reg) {
        int i = i0 + quad * 4 + reg;
        float v = acc[reg] * c0n
                + base0[((size_t)(b * NNODE + i)) * 64 + e]
                + (sb + r_lds[i]) * s2 + r2;
        outp[((size_t)(b * NNODE + i)) * 64 + e] = v;
    }
}

extern "C" void kernel_launch(void* const* d_in, const int* in_sizes, int n_in,
                              void* d_out, int out_size, void* d_ws, size_t ws_size,
                              hipStream_t stream) {
    const float* A      = (const float*)d_in[0];
    const float* X      = (const float*)d_in[1];
    const float* coeffs = (const float*)d_in[2];
    const float* wA1    = (const float*)d_in[3];
    const float* wA2    = (const float*)d_in[4];
    const float* w11    = (const float*)d_in[5];
    const float* w12    = (const float*)d_in[6];
    const float* w13    = (const float*)d_in[7];
    const float* w14    = (const float*)d_in[8];
    const float* w15    = (const float*)d_in[9];
    const float* w16    = (const float*)d_in[10];
    const float* w21    = (const float*)d_in[11];
    const float* w22    = (const float*)d_in[12];
    const float* w23    = (const float*)d_in[13];
    const float* w24    = (const float*)d_in[14];
    const float* w25    = (const float*)d_in[15];
    const float* w26    = (const float*)d_in[16];

    float* ws  = (float*)d_ws;
    float* At  = (float*)d_out;
    float* out = (float*)d_out + (size_t)NGRAPH * NNODE * NNODE;

    float* rowsum = ws + OFF_ROWSUM;
    float* diagv  = ws + OFF_DIAG;
    float* p1     = ws + OFF_P1;
    float* rws    = ws + OFF_R;
    float* cspart = ws + OFF_CS;
    float* sArr   = ws + OFF_S;
    float* S2part = ws + OFF_S2P;
    float* R2part = ws + OFF_R2P;
    float* base0  = ws + OFF_BASE0;
    unsigned short* x2tg = (unsigned short*)(ws + OFF_X2T);

    kA_stats<<<NGRAPH * NNODE / 4 + NGRAPH * 8, 256, 0, stream>>>(
        A, X, wA1, rowsum, diagv, p1, cspart);
    kB_nodes<<<NGRAPH * 16, 256, 0, stream>>>(
        X, coeffs, wA2, w11, w12, w13, w14, w15, w16,
        w21, w22, w23, w24, w25, w26,
        rowsum, diagv, cspart, p1,
        rws, base0, x2tg, S2part, R2part, sArr);
    kC_main<<<NGRAPH * 64, 256, 0, stream>>>(
        A, coeffs, sArr, rws, x2tg, base0, S2part, R2part, At, out);
}

// Round 6
// 202.535 us; speedup vs baseline: 1.0976x; 1.0976x over previous
//
#include <hip/hip_runtime.h>
#include <hip/hip_bf16.h>

#define NGRAPH 16
#define NNODE 1024
#define DDIM 64

typedef __attribute__((ext_vector_type(8))) short bf16x8;
typedef __attribute__((ext_vector_type(4))) float f32x4;

// ---- workspace layout (float offsets) ----
#define OFF_ROWSUM 0            // 16384
#define OFF_DIAG   16384        // 16384
#define OFF_P1     32768        // 16384
#define OFF_R      49152        // 16384
#define OFF_CS     65536        // 16*8*64 = 8192
#define OFF_S      73728        // 16 (+ pad)
#define OFF_S2P    75840        // 16384
#define OFF_R2P    92224        // 16384
#define OFF_BASE0  110656       // 16*1024*64 = 1048576
#define OFF_X2T    1159232      // ushort area: 16*64*1024 ushorts = 524288 floats

__device__ __forceinline__ unsigned short f2bf(float f) {
    unsigned int u = __float_as_uint(f);
    u = (u + 0x7fffu + ((u >> 16) & 1u)) >> 16;
    return (unsigned short)u;
}

__device__ __forceinline__ float wave_reduce(float v) {
    #pragma unroll
    for (int off = 32; off; off >>= 1) v += __shfl_down(v, off, 64);
    return v;
}

// ---------------- kA: A row sums + diag  |  X column sums + p1 = X @ wA1 ----------------
__global__ __launch_bounds__(256) void kA_stats(const float* __restrict__ A,
                                                const float* __restrict__ X,
                                                const float* __restrict__ wA1,
                                                float* __restrict__ rowsum,
                                                float* __restrict__ diagv,
                                                float* __restrict__ p1,
                                                float* __restrict__ colsum_part) {
    if (blockIdx.x < NGRAPH * NNODE / 4) {
        int row  = blockIdx.x * 4 + (threadIdx.x >> 6);
        int lane = threadIdx.x & 63;
        const float4* b4 = (const float4*)(A + (size_t)row * NNODE);
        float sum = 0.f;
        #pragma unroll
        for (int it = 0; it < 4; ++it) {
            float4 v = b4[lane + it * 64];
            sum += v.x + v.y + v.z + v.w;
        }
        sum = wave_reduce(sum);
        if (lane == 0) {
            rowsum[row] = sum;
            int i = row & (NNODE - 1);
            diagv[row] = ((const float*)b4)[i];
        }
    } else {
        int bid  = blockIdx.x - NGRAPH * NNODE / 4;
        int b    = bid >> 3;
        int blk  = bid & 7;
        int wv   = threadIdx.x >> 6;
        int lane = threadIdx.x & 63;
        float w = wA1[lane];
        float cs = 0.f;
        int row0 = blk * 128 + wv * 32;
        const float* Xb = X + (size_t)b * NNODE * DDIM;
        for (int rI = 0; rI < 32; ++rI) {
            int i = row0 + rI;
            float x = Xb[i * DDIM + lane];
            cs += x;
            float v = wave_reduce(x * w);
            if (lane == 0) p1[b * NNODE + i] = v;
        }
        __shared__ float csl[4][64];
        csl[wv][lane] = cs;
        __syncthreads();
        if (threadIdx.x < 64) {
            float t = csl[0][lane] + csl[1][lane] + csl[2][lane] + csl[3][lane];
            colsum_part[(b * 8 + blk) * 64 + lane] = t;
        }
    }
}

// ---------------- kB: per-graph stats (recomputed per block) + per-node transforms ----------------
__global__ __launch_bounds__(256) void kB_nodes(const float* __restrict__ X,
                                                const float* __restrict__ coeffs,
                                                const float* __restrict__ wA2,
                                                const float* __restrict__ w11,
                                                const float* __restrict__ w12,
                                                const float* __restrict__ w13,
                                                const float* __restrict__ w14,
                                                const float* __restrict__ w15,
                                                const float* __restrict__ w16,
                                                const float* __restrict__ w21,
                                                const float* __restrict__ w22,
                                                const float* __restrict__ w23,
                                                const float* __restrict__ w24,
                                                const float* __restrict__ w25,
                                                const float* __restrict__ w26,
                                                const float* __restrict__ rowsum,
                                                const float* __restrict__ diagv,
                                                const float* __restrict__ colsum_part,
                                                const float* __restrict__ p1g,
                                                float* __restrict__ rws,
                                                float* __restrict__ base0,
                                                unsigned short* __restrict__ x2tg,
                                                float* __restrict__ S2part,
                                                float* __restrict__ R2part,
                                                float* __restrict__ sArr) {
    __shared__ float Xl[64][68];
    __shared__ float w1l[64][68];
    __shared__ float w2l[64][68];
    __shared__ unsigned short X2Tl[64][68];
    __shared__ float rm_l[64], dg_l[64], r_l[64];
    __shared__ float redS[4][64], redR[4][64];
    __shared__ float redA[4], redD[4];
    __shared__ float mxs[64], p2s;
    __shared__ float pg1_l[64], pg2_l[64];

    int b    = blockIdx.x >> 4;
    int tile = blockIdx.x & 15;
    int i0   = tile * 64;
    int tid  = threadIdx.x;
    int e    = tid & 63;
    int wv   = tid >> 6;

    // --- stage X tile + weights ---
    const float* Xg = X + (size_t)b * (NNODE * DDIM) + (size_t)i0 * DDIM;
    #pragma unroll
    for (int it = 0; it < 4; ++it) {
        int g   = it * 256 + tid;
        int row = g >> 4;
        int c4  = (g & 15) << 2;
        float4 v  = ((const float4*)Xg)[g];
        *(float4*)&Xl[row][c4] = v;
        float4 v1 = ((const float4*)w11)[g];
        *(float4*)&w1l[row][c4] = v1;
        float4 v2 = ((const float4*)w21)[g];
        *(float4*)&w2l[row][c4] = v2;
    }

    // --- per-graph scalar stats (every block recomputes; cheap) ---
    float sa = 0.f, sd = 0.f;
    for (int i = tid; i < NNODE; i += 256) {
        sa += rowsum[b * NNODE + i];
        sd += diagv[b * NNODE + i];
    }
    sa = wave_reduce(sa); sd = wave_reduce(sd);
    if (e == 0) { redA[wv] = sa; redD[wv] = sd; }
    if (tid < 64) {
        float mx = 0.f;
        for (int k = 0; k < 8; ++k) mx += colsum_part[(b * 8 + k) * 64 + tid];
        mxs[tid] = mx * (1.f / (float)NNODE);
    }
    __syncthreads();
    float mean_all  = (redA[0] + redA[1] + redA[2] + redA[3]) * (1.f / ((float)NNODE * (float)NNODE));
    float mean_diag = (redD[0] + redD[1] + redD[2] + redD[3]) * (1.f / (float)NNODE);
    if (tid < 64) {
        float v = wave_reduce(mxs[tid] * wA2[tid]);
        if (tid == 0) p2s = v;
    }
    if (tid < 64) {
        float a1 = 0.f, a2 = 0.f;
        for (int d = 0; d < 64; ++d) {
            float m = mxs[d];
            a1 += m * w12[tid * 64 + d];
            a2 += m * w22[tid * 64 + d];
        }
        pg1_l[tid] = a1 + mean_diag * w15[tid] + mean_all * w16[tid];
        pg2_l[tid] = a2 + mean_diag * w25[tid] + mean_all * w26[tid];
    }
    float c3 = coeffs[3], c4c = coeffs[4];
    if (tid < 64) {
        float rs  = rowsum[b * NNODE + i0 + tid];
        float dgv = diagv[b * NNODE + i0 + tid];
        float rmv = rs * (1.f / (float)NNODE);
        rm_l[tid] = rmv;
        dg_l[tid] = dgv;
        float rv = c3 * rmv + c4c * dgv + p1g[b * NNODE + i0 + tid];
        r_l[tid] = rv;
        rws[b * NNODE + i0 + tid] = rv;
    }
    __syncthreads();
    if (tile == 0 && tid == 0)
        sArr[b] = coeffs[1] * mean_all + coeffs[2] * mean_diag + p2s;

    float w13e = w13[e], w14e = w14[e], w23e = w23[e], w24e = w24[e];
    float pg1e = pg1_l[e], pg2e = pg2_l[e];

    float acc1[16], acc2[16];
    #pragma unroll
    for (int t = 0; t < 16; ++t) { acc1[t] = 0.f; acc2[t] = 0.f; }

    for (int d0 = 0; d0 < 64; d0 += 4) {
        float4 w1v = *(const float4*)&w1l[e][d0];
        float4 w2v = *(const float4*)&w2l[e][d0];
        #pragma unroll
        for (int t = 0; t < 16; ++t) {
            int li = wv + 4 * t;
            float4 xv = *(const float4*)&Xl[li][d0];
            acc1[t] += xv.x * w1v.x + xv.y * w1v.y + xv.z * w1v.z + xv.w * w1v.w;
            acc2[t] += xv.x * w2v.x + xv.y * w2v.y + xv.z * w2v.z + xv.w * w2v.w;
        }
    }

    float s2acc = 0.f, r2acc = 0.f;
    #pragma unroll
    for (int t = 0; t < 16; ++t) {
        int li = wv + 4 * t;
        int i  = i0 + li;
        float rmv = rm_l[li], dgv = dg_l[li];
        float x2t = acc2[t] + rmv * w23e + dgv * w24e + pg2e;
        float b0  = acc1[t] + rmv * w13e + dgv * w14e + pg1e;
        base0[((size_t)(b * NNODE + i)) * 64 + e] = b0;
        X2Tl[e][li] = f2bf(x2t);
        s2acc += x2t;
        r2acc += r_l[li] * x2t;
    }
    redS[wv][e] = s2acc;
    redR[wv][e] = r2acc;
    __syncthreads();

    for (int k = 0; k < 16; ++k) {
        int ep = wv * 16 + k;
        unsigned short v = X2Tl[ep][e];
        x2tg[((size_t)(b * 64 + ep)) * NNODE + i0 + e] = v;
    }
    if (tid < 64) {
        float s2 = redS[0][tid] + redS[1][tid] + redS[2][tid] + redS[3][tid];
        float r2 = redR[0][tid] + redR[1][tid] + redR[2][tid] + redR[3][tid];
        S2part[(b * 16 + tile) * 64 + tid] = s2;
        R2part[(b * 16 + tile) * 64 + tid] = r2;
    }
}

// ---------------- kC: fused A_t + bf16 MFMA c0*(A @ X2t) + epilogue ----------------
// R4 structure (LDS-staged A, double-buffered, B from L2-resident ws) with:
//  - lgkm-only barrier (inline asm): At stores are fire-and-forget, no vmcnt(0)
//    drain per K-iter (the m97-style structural stall)
//  - A-tile global loads software-pipelined one kt ahead (vmcnt wait lands at
//    use, after the barrier, not at the barrier)
//  - LDS row stride 132 ushorts (66 words -> 2-way bank aliasing = free)
__global__ __launch_bounds__(256) void kC_main(const float* __restrict__ A,
                                               const float* __restrict__ coeffs,
                                               const float* __restrict__ sArr,
                                               const float* __restrict__ rArr,
                                               const unsigned short* __restrict__ x2tg,
                                               const float* __restrict__ base0,
                                               const float* __restrict__ S2part,
                                               const float* __restrict__ R2part,
                                               float* __restrict__ At,
                                               float* __restrict__ outp) {
    __shared__ unsigned short Al[2][16][132];
    __shared__ float r_lds[1024];
    __shared__ float s2_lds[64], r2_lds[64];

    int b    = blockIdx.x >> 6;      // 64 tiles of 16 rows per graph
    int tile = blockIdx.x & 63;
    int i0   = tile * 16;
    int tid  = threadIdx.x;

    // stage r (1024 floats); threads<64 also reduce S2/R2 partials
    float4 rv = ((const float4*)(rArr + b * NNODE))[tid];
    *(float4*)&r_lds[tid * 4] = rv;
    if (tid < 64) {
        float s2 = 0.f, r2 = 0.f;
        #pragma unroll
        for (int t = 0; t < 16; ++t) {
            s2 += S2part[(b * 16 + t) * 64 + tid];
            r2 += R2part[(b * 16 + t) * 64 + tid];
        }
        s2_lds[tid] = s2 * (1.f / (float)NNODE);
        r2_lds[tid] = r2 * (1.f / (float)NNODE);
    }

    float sb  = sArr[b];
    float c0  = coeffs[0];
    float c0n = c0 * (1.f / (float)NNODE);

    int arow = tid >> 4;             // 0..15
    int acol = (tid & 15) * 8;       // 0..120
    const float* Ab  = A  + ((size_t)(b * NNODE + i0 + arow)) * NNODE + acol;
    float*       Atb = At + ((size_t)(b * NNODE + i0 + arow)) * NNODE + acol;

    int lane = tid & 63, wv = tid >> 6;    // wv 0..3
    int m = lane & 15, quad = lane >> 4;
    int e = wv * 16 + m;
    const unsigned short* Bg = x2tg + ((size_t)(b * 64 + e)) * NNODE + quad * 8;

    // prefetch kt=0 A-tile into registers (no barrier dependency)
    float4 a0 = *(const float4*)(Ab);
    float4 a1 = *(const float4*)(Ab + 4);

    f32x4 acc = {0.f, 0.f, 0.f, 0.f};

    __syncthreads();   // full barrier, once: r_lds / s2_lds ready

    float bse = sb + r_lds[i0 + arow];

    for (int kt = 0; kt < 8; ++kt) {
        // ---- B fragments for this K-chunk (L2-resident; vmcnt wait at MFMA) ----
        bf16x8 bf0 = *(const bf16x8*)(Bg + kt * 128);
        bf16x8 bf1 = *(const bf16x8*)(Bg + kt * 128 + 32);
        bf16x8 bf2 = *(const bf16x8*)(Bg + kt * 128 + 64);
        bf16x8 bf3 = *(const bf16x8*)(Bg + kt * 128 + 96);

        // ---- A_t compute + store (fire-and-forget) + bf16 pack into LDS ----
        int cidx = kt * 128 + acol;
        float4 rj0 = *(const float4*)&r_lds[cidx];
        float4 rj1 = *(const float4*)&r_lds[cidx + 4];
        f32x4 t0, t1;
        t0.x = fmaf(c0, a0.x, bse + rj0.x);
        t0.y = fmaf(c0, a0.y, bse + rj0.y);
        t0.z = fmaf(c0, a0.z, bse + rj0.z);
        t0.w = fmaf(c0, a0.w, bse + rj0.w);
        t1.x = fmaf(c0, a1.x, bse + rj1.x);
        t1.y = fmaf(c0, a1.y, bse + rj1.y);
        t1.z = fmaf(c0, a1.z, bse + rj1.z);
        t1.w = fmaf(c0, a1.w, bse + rj1.w);
        *(f32x4*)(Atb + kt * 128)     = t0;
        *(f32x4*)(Atb + kt * 128 + 4) = t1;

        uint4 pk;
        pk.x = (unsigned int)f2bf(a0.x) | ((unsigned int)f2bf(a0.y) << 16);
        pk.y = (unsigned int)f2bf(a0.z) | ((unsigned int)f2bf(a0.w) << 16);
        pk.z = (unsigned int)f2bf(a1.x) | ((unsigned int)f2bf(a1.y) << 16);
        pk.w = (unsigned int)f2bf(a1.z) | ((unsigned int)f2bf(a1.w) << 16);
        *(uint4*)&Al[kt & 1][arow][acol] = pk;

        // ---- prefetch next kt's A-tile (completes after the barrier, at use) ----
        if (kt < 7) {
            a0 = *(const float4*)(Ab + (kt + 1) * 128);
            a1 = *(const float4*)(Ab + (kt + 1) * 128 + 4);
        }

        // ---- lgkm-only barrier: LDS writes visible; NO vmcnt drain ----
        asm volatile("s_waitcnt lgkmcnt(0)\n\ts_barrier" ::: "memory");

        // ---- MFMA: 4 K-steps of 32 ----
        bf16x8 av0 = *(const bf16x8*)&Al[kt & 1][m][quad * 8];
        bf16x8 av1 = *(const bf16x8*)&Al[kt & 1][m][32 + quad * 8];
        bf16x8 av2 = *(const bf16x8*)&Al[kt & 1][m][64 + quad * 8];
        bf16x8 av3 = *(const bf16x8*)&Al[kt & 1][m][96 + quad * 8];
        acc = __builtin_amdgcn_mfma_f32_16x16x32_bf16(av0, bf0, acc, 0, 0, 0);
        acc = __builtin_amdgcn_mfma_f32_16x16x32_bf16(av1, bf1, acc, 0, 0, 0);
        acc = __builtin_amdgcn_mfma_f32_16x16x32_bf16(av2, bf2, acc, 0, 0, 0);
        acc = __builtin_amdgcn_mfma_f32_16x16x32_bf16(av3, bf3, acc, 0, 0, 0);
    }

    // ---- epilogue: out = c0/n * (A@X2t) + base0 + (s + r_i)*S2/n + R2/n ----
    float s2 = s2_lds[e];
    float r2 = r2_lds[e];
    #pragma unroll
    for (int reg = 0; reg < 4; ++reg) {
        int i = i0 + quad * 4 + reg;
        float v = acc[reg] * c0n
                + base0[((size_t)(b * NNODE + i)) * 64 + e]
                + (sb + r_lds[i]) * s2 + r2;
        outp[((size_t)(b * NNODE + i)) * 64 + e] = v;
    }
}

extern "C" void kernel_launch(void* const* d_in, const int* in_sizes, int n_in,
                              void* d_out, int out_size, void* d_ws, size_t ws_size,
                              hipStream_t stream) {
    const float* A      = (const float*)d_in[0];
    const float* X      = (const float*)d_in[1];
    const float* coeffs = (const float*)d_in[2];
    const float* wA1    = (const float*)d_in[3];
    const float* wA2    = (const float*)d_in[4];
    const float* w11    = (const float*)d_in[5];
    const float* w12    = (const float*)d_in[6];
    const float* w13    = (const float*)d_in[7];
    const float* w14    = (const float*)d_in[8];
    const float* w15    = (const float*)d_in[9];
    const float* w16    = (const float*)d_in[10];
    const float* w21    = (const float*)d_in[11];
    const float* w22    = (const float*)d_in[12];
    const float* w23    = (const float*)d_in[13];
    const float* w24    = (const float*)d_in[14];
    const float* w25    = (const float*)d_in[15];
    const float* w26    = (const float*)d_in[16];

    float* ws  = (float*)d_ws;
    float* At  = (float*)d_out;
    float* out = (float*)d_out + (size_t)NGRAPH * NNODE * NNODE;

    float* rowsum = ws + OFF_ROWSUM;
    float* diagv  = ws + OFF_DIAG;
    float* p1     = ws + OFF_P1;
    float* rws    = ws + OFF_R;
    float* cspart = ws + OFF_CS;
    float* sArr   = ws + OFF_S;
    float* S2part = ws + OFF_S2P;
    float* R2part = ws + OFF_R2P;
    float* base0  = ws + OFF_BASE0;
    unsigned short* x2tg = (unsigned short*)(ws + OFF_X2T);

    kA_stats<<<NGRAPH * NNODE / 4 + NGRAPH * 8, 256, 0, stream>>>(
        A, X, wA1, rowsum, diagv, p1, cspart);
    kB_nodes<<<NGRAPH * 16, 256, 0, stream>>>(
        X, coeffs, wA2, w11, w12, w13, w14, w15, w16,
        w21, w22, w23, w24, w25, w26,
        rowsum, diagv, cspart, p1,
        rws, base0, x2tg, S2part, R2part, sArr);
    kC_main<<<NGRAPH * 64, 256, 0, stream>>>(
        A, coeffs, sArr, rws, x2tg, base0, S2part, R2part, At, out);
}